// Round 5
// baseline (161.325 us; speedup 1.0000x reference)
//
#include <hip/hip_runtime.h>

// GraphNet interaction network. Edge MLP via bf16 MFMA (fp32 accum).
// V14: TWO EDGE-STREAMS PER WAVE. Round-4 arithmetic: per-wave wall ~21k cyc
// vs ~320 cyc/tile issue demand -> the wave is latency-bound on its own
// MFMA->pack->MFMA chain with ~1.3 waves/SIMD resident. Occupancy was proven
// (r2) not to be the lever, so add ILP instead: each wave owns TWO (b,recv)
// pairs sharing all weight/bias registers; tile bodies interleaved at s-step
// granularity so stream B's MFMAs issue inside stream A's latency shadows.
// Halves wave count (grid 752), halves per-wave prologue cost per unit work.
// V13 retained: zero LDS, no syncthreads, peeled s=0/s2=0 bias C-init,
// mask only on tile 11, cvt_pk relu-pack, E1 prefetch.
// V9 core retained: operand-swapped edge MLP, edges on N, layer-l C output is
// layer-(l+1) B-fragment under k-permutation baked into W2/W3 at prep.
#define BB   32
#define NN   188
#define PP   16
#define HID  128
#define HH2  64
#define DE   5
#define DO   6
#define NT   5
#define ROWS_O (BB*NN)
#define RT   32
#define KO   (PP+DE)

typedef __attribute__((ext_vector_type(8))) short short8;     // 8 bf16 = 4 VGPRs
typedef __attribute__((ext_vector_type(4))) float float4_;
typedef __attribute__((ext_vector_type(4))) unsigned uint4_;

__device__ __forceinline__ short f2bf(float v) {              // RNE (prep only)
    union { float f; unsigned u; } a; a.f = v;
    unsigned r = a.u + 0x7fff + ((a.u >> 16) & 1);
    return (short)(r >> 16);
}
// relu both, then pack to 2xbf16 (RNE): low16 = bf16(max(lo,0)), high16 = bf16(max(hi,0))
__device__ __forceinline__ unsigned relu_pk(float lo, float hi) {
    float l = lo > 0.f ? lo : 0.f;
    float h = hi > 0.f ? hi : 0.f;
    unsigned r;
    asm("v_cvt_pk_bf16_f32 %0, %1, %2" : "=v"(r) : "v"(l), "v"(h));
    return r;
}
__device__ __forceinline__ float4_ mfma16(short8 a, short8 b, float4_ c) {
    return __builtin_amdgcn_mfma_f32_16x16x32_bf16(a, b, c, 0, 0, 0);
}

// workspace layout (shorts)
#define XB_OFF    0                        // bf16 [32][188][24]
#define XB_ELTS   (BB*NN*24)               // 144384
#define W1S_OFF   (XB_OFF + XB_ELTS)       // A-frags [8 f][64 lanes][8]
#define W1S_ELTS  (8*64*8)                 // 4096
#define W2S_OFF   (W1S_OFF + W1S_ELTS)     // A-frags [16 f][64 lanes][8]
#define W2S_ELTS  (16*64*8)                // 8192
#define W3S_OFF   (W2S_OFF + W2S_ELTS)     // A-frags [2 s][64 lanes][8]
#define W3S_ELTS  (2*64*8)                 // 1024
#define SHORT_TOTAL (W3S_OFF + W3S_ELTS)

// MFMA-k position (q, e) -> neuron offset within a 32-block
__device__ __forceinline__ int kmap(int q, int e) {
    return (e < 4) ? (q*4 + e) : (16 + q*4 + (e - 4));
}

__global__ void prep_kernel(const float* __restrict__ x,
                            const float* __restrict__ w1,
                            const float* __restrict__ w2,
                            const float* __restrict__ w3,
                            short* __restrict__ ws)
{
    const int i = blockIdx.x * blockDim.x + threadIdx.x;
    const int stride = gridDim.x * blockDim.x;
    for (int idx = i; idx < BB*NN*PP; idx += stride) {       // x -> xb
        int row = idx >> 4, k = idx & 15;
        ws[XB_OFF + row*24 + k] = f2bf(x[idx]);
    }
    for (int idx = i; idx < W1S_ELTS; idx += stride) {       // w1 -> A-frags
        int t = idx >> 9;            // frag 0..7 (16-neuron block)
        int l = (idx >> 3) & 63;     // lane
        int e = idx & 7;
        int q = l >> 4, n16 = l & 15;
        // A-operand element: row n = t*16+n16, k = q*8+e; w1 is [k=32][n=128]
        ws[W1S_OFF + idx] = f2bf(w1[(q*8 + e)*HID + t*16 + n16]);
    }
    for (int idx = i; idx < W2S_ELTS; idx += stride) {       // w2 -> A-frags
        int f = idx >> 9;            // frag = tt*4 + s
        int l = (idx >> 3) & 63;     // lane
        int e = idx & 7;
        int tt = f >> 2, s = f & 3;
        int q = l >> 4, n16 = l & 15;
        int k = 32*s + kmap(q, e);
        int n = tt*16 + n16;
        ws[W2S_OFF + idx] = f2bf(w2[k*HH2 + n]);
    }
    for (int idx = i; idx < W3S_ELTS; idx += stride) {       // w3 -> A-frags
        int s2 = idx >> 9;
        int l = (idx >> 3) & 63;
        int e = idx & 7;
        int q = l >> 4, n16 = l & 15;
        int k = 32*s2 + kmap(q, e);
        ws[W3S_OFF + idx] = (n16 < DE) ? f2bf(w3[k*DE + n16]) : (short)0;
    }
}

// One fused edge-tile over TWO independent streams (A,B). Stream-B MFMAs are
// interleaved into stream-A latency shadows. s=0 / s2=0 peeled: bias enters
// as the MFMA C-operand. MASKED only for the final (padded) tile; the mask
// depends only on the edge index so it is shared by both streams.
template<bool MASKED>
__device__ __forceinline__ void edge_tile2(
    const short8* W1f, const short8* W2f, const short8* W3f,
    const float4_* cbv, const float4_* bias2v, float4_ bias3r,
    short8 EA, short8 EB, float* accA, float* accB, bool ok)
{
    float4_ C2A[4], C2B[4];
    { // s = 0: C2 init via MFMA C-operand = bias2v
        float4_ CaA = mfma16(W1f[0], EA, cbv[0]);
        float4_ CbA = mfma16(W1f[1], EA, cbv[1]);
        float4_ CaB = mfma16(W1f[0], EB, cbv[0]);
        float4_ CbB = mfma16(W1f[1], EB, cbv[1]);
        uint4_ dA = (uint4_){ relu_pk(CaA[0], CaA[1]), relu_pk(CaA[2], CaA[3]),
                              relu_pk(CbA[0], CbA[1]), relu_pk(CbA[2], CbA[3]) };
        short8 BfA = __builtin_bit_cast(short8, dA);
        uint4_ dB = (uint4_){ relu_pk(CaB[0], CaB[1]), relu_pk(CaB[2], CaB[3]),
                              relu_pk(CbB[0], CbB[1]), relu_pk(CbB[2], CbB[3]) };
        short8 BfB = __builtin_bit_cast(short8, dB);
        #pragma unroll
        for (int tt = 0; tt < 4; ++tt) {
            C2A[tt] = mfma16(W2f[tt*4], BfA, bias2v[tt]);
            C2B[tt] = mfma16(W2f[tt*4], BfB, bias2v[tt]);
        }
    }
    #pragma unroll
    for (int s = 1; s < 4; ++s) {
        float4_ CaA = mfma16(W1f[2*s],   EA, cbv[2*s]);
        float4_ CbA = mfma16(W1f[2*s+1], EA, cbv[2*s+1]);
        float4_ CaB = mfma16(W1f[2*s],   EB, cbv[2*s]);
        float4_ CbB = mfma16(W1f[2*s+1], EB, cbv[2*s+1]);
        uint4_ dA = (uint4_){ relu_pk(CaA[0], CaA[1]), relu_pk(CaA[2], CaA[3]),
                              relu_pk(CbA[0], CbA[1]), relu_pk(CbA[2], CbA[3]) };
        short8 BfA = __builtin_bit_cast(short8, dA);
        uint4_ dB = (uint4_){ relu_pk(CaB[0], CaB[1]), relu_pk(CaB[2], CaB[3]),
                              relu_pk(CbB[0], CbB[1]), relu_pk(CbB[2], CbB[3]) };
        short8 BfB = __builtin_bit_cast(short8, dB);
        #pragma unroll
        for (int tt = 0; tt < 4; ++tt) {
            C2A[tt] = mfma16(W2f[tt*4 + s], BfA, C2A[tt]);
            C2B[tt] = mfma16(W2f[tt*4 + s], BfB, C2B[tt]);
        }
    }
    // layer 3: s2=0 peeled (bias3r as C-in), streams interleaved
    float4_ C3A, C3B;
    {
        uint4_ dA = (uint4_){ relu_pk(C2A[0][0], C2A[0][1]), relu_pk(C2A[0][2], C2A[0][3]),
                              relu_pk(C2A[1][0], C2A[1][1]), relu_pk(C2A[1][2], C2A[1][3]) };
        uint4_ dB = (uint4_){ relu_pk(C2B[0][0], C2B[0][1]), relu_pk(C2B[0][2], C2B[0][3]),
                              relu_pk(C2B[1][0], C2B[1][1]), relu_pk(C2B[1][2], C2B[1][3]) };
        C3A = mfma16(W3f[0], __builtin_bit_cast(short8, dA), bias3r);
        C3B = mfma16(W3f[0], __builtin_bit_cast(short8, dB), bias3r);
    }
    {
        uint4_ dA = (uint4_){ relu_pk(C2A[2][0], C2A[2][1]), relu_pk(C2A[2][2], C2A[2][3]),
                              relu_pk(C2A[3][0], C2A[3][1]), relu_pk(C2A[3][2], C2A[3][3]) };
        uint4_ dB = (uint4_){ relu_pk(C2B[2][0], C2B[2][1]), relu_pk(C2B[2][2], C2B[2][3]),
                              relu_pk(C2B[3][0], C2B[3][1]), relu_pk(C2B[3][2], C2B[3][3]) };
        C3A = mfma16(W3f[1], __builtin_bit_cast(short8, dA), C3A);
        C3B = mfma16(W3f[1], __builtin_bit_cast(short8, dB), C3B);
    }
    if (MASKED) {
        #pragma unroll
        for (int rg = 0; rg < 4; ++rg) {
            float va = C3A[rg] > 0.f ? C3A[rg] : 0.f;
            float vb = C3B[rg] > 0.f ? C3B[rg] : 0.f;
            accA[rg] += ok ? va : 0.f;
            accB[rg] += ok ? vb : 0.f;
        }
    } else {
        #pragma unroll
        for (int rg = 0; rg < 4; ++rg) {
            accA[rg] += C3A[rg] > 0.f ? C3A[rg] : 0.f;
            accB[rg] += C3B[rg] > 0.f ? C3B[rg] : 0.f;
        }
    }
}

// Per-stream E1 fragment load (node features for this lane's edge)
__device__ __forceinline__ short8 load_e1(const short* xrow, int recv, int e,
                                          bool rside, int qoff) {
    int send = e + (e >= recv ? 1 : 0);
    if (send > NN-1) send = NN-1;                // clamp padding rows
    const int node = rside ? recv : send;
    return *(const short8*)(xrow + node*24 + qoff);
}

// ---------------------------------------------------------------------------
// Edge MLP: 32 -> 128 relu -> 64 relu -> 5 relu, summed over 187 edges of one
// (batch, receiver). TWO receivers PER WAVE (ILP); 4 waves per block; ZERO LDS.
// All weights/biases register-resident; 12 fused edge-tiles of 16 per wave.
// ---------------------------------------------------------------------------
__global__ __launch_bounds__(256) __attribute__((amdgpu_waves_per_eu(2, 2)))
void edge_mfma_kernel(const short* __restrict__ ws_s,
                      const float* __restrict__ b1,
                      const float* __restrict__ b2,
                      const float* __restrict__ b3,
                      float* __restrict__ ebar)
{
    const short* xb  = ws_s + XB_OFF;
    const short* w1g = ws_s + W1S_OFF;
    const short* w2g = ws_s + W2S_OFF;
    const short* w3g = ws_s + W3S_OFF;

    const int tid  = threadIdx.x;
    const int wave = tid >> 6;
    const int lane = tid & 63;
    const int n16  = lane & 15;
    const int q    = lane >> 4;
    const int bi0  = blockIdx.x * 8 + wave * 2;  // stream A: b*188 + recv
    const int bi1  = bi0 + 1;                    // stream B
    const int bA   = bi0 / NN, recvA = bi0 - bA*NN;
    const int bB   = bi1 / NN, recvB = bi1 - bB*NN;

    // ---- register-resident operands (all loop-invariant, coalesced loads) ----
    short8 W1f[8];
    #pragma unroll
    for (int t = 0; t < 8; ++t)
        W1f[t] = *(const short8*)(w1g + t*512 + lane*8);
    short8 W2f[16];
    #pragma unroll
    for (int f = 0; f < 16; ++f)
        W2f[f] = *(const short8*)(w2g + f*512 + lane*8);
    short8 W3f[2];
    #pragma unroll
    for (int s = 0; s < 2; ++s)
        W3f[s] = *(const short8*)(w3g + s*512 + lane*8);
    float4_ cbv[8];                                   // layer-1 bias C-init
    #pragma unroll
    for (int t = 0; t < 8; ++t)
        cbv[t] = *(const float4_*)(b1 + t*16 + q*4);
    float4_ bias2v[4];                                // layer-2 bias C-init
    #pragma unroll
    for (int tt = 0; tt < 4; ++tt)
        bias2v[tt] = *(const float4_*)(b2 + tt*16 + q*4);
    float4_ bias3r;                                   // layer-3 bias C-init
    #pragma unroll
    for (int rg = 0; rg < 4; ++rg) {
        int o = q*4 + rg;
        bias3r[rg] = (o < DE) ? b3[o] : 0.f;
    }

    const short* xrowA = xb + bA*(NN*24);
    const short* xrowB = xb + bB*(NN*24);
    const bool rside = (q < 2);                  // lanes q<2 read recv, q>=2 send
    const int qoff = (q & 1)*8;

    float accA[4] = {0.f, 0.f, 0.f, 0.f};
    float accB[4] = {0.f, 0.f, 0.f, 0.f};

    // prefetch tile-0 node features for both streams
    short8 EA = load_e1(xrowA, recvA, n16, rside, qoff);
    short8 EB = load_e1(xrowB, recvB, n16, rside, qoff);

    #pragma unroll 1
    for (int ti = 0; ti < 11; ++ti) {
        short8 EAc = EA, EBc = EB;
        EA = load_e1(xrowA, recvA, (ti+1)*16 + n16, rside, qoff);   // prefetch
        EB = load_e1(xrowB, recvB, (ti+1)*16 + n16, rside, qoff);
        edge_tile2<false>(W1f, W2f, W3f, cbv, bias2v, bias3r,
                          EAc, EBc, accA, accB, true);
    }
    edge_tile2<true>(W1f, W2f, W3f, cbv, bias2v, bias3r,
                     EA, EB, accA, accB, (11*16 + n16 < NN-1));

    // reduce over the 16 edge-columns (n16 direction) — wave-local only
    #pragma unroll
    for (int rg = 0; rg < 4; ++rg) {
        accA[rg] += __shfl_xor(accA[rg], 1);
        accA[rg] += __shfl_xor(accA[rg], 2);
        accA[rg] += __shfl_xor(accA[rg], 4);
        accA[rg] += __shfl_xor(accA[rg], 8);
        accB[rg] += __shfl_xor(accB[rg], 1);
        accB[rg] += __shfl_xor(accB[rg], 2);
        accB[rg] += __shfl_xor(accB[rg], 4);
        accB[rg] += __shfl_xor(accB[rg], 8);
    }
    if (n16 == 0) {
        #pragma unroll
        for (int rg = 0; rg < 4; ++rg) {
            int o = q*4 + rg;
            if (o < DE) {
                ebar[bi0*DE + o] = accA[rg];
                ebar[bi1*DE + o] = accB[rg];
            }
        }
    }
}

// ---------------------------------------------------------------------------
// Object MLP (unchanged): [x(16)|Ebar(5)] -> 128 -> 64 -> 6 relu
// ---------------------------------------------------------------------------
__global__ __launch_bounds__(512)
void obj_mlp_kernel(const float* __restrict__ x, const float* __restrict__ ebar,
                    const float* __restrict__ w1, const float* __restrict__ b1,
                    const float* __restrict__ w2, const float* __restrict__ b2,
                    const float* __restrict__ w3, const float* __restrict__ b3,
                    float* __restrict__ o_out)
{
    __shared__ float sW[HID*HH2];
    __shared__ float sB1[HID];
    __shared__ float sB2[HH2];
    __shared__ float sCin[RT*KO];
    __shared__ float sH1[RT*HID];
    __shared__ float sH2t[HH2*(RT+1)];
    const int tid = threadIdx.x;
    const int rbase = blockIdx.x * RT;

    for (int i = tid; i < KO*HID; i += 512) sW[i] = w1[i];
    if (tid < HID) sB1[tid] = b1[tid];
    else if (tid < HID+HH2) sB2[tid-HID] = b2[tid-HID];
    for (int i = tid; i < RT*KO; i += 512) {
        int r = i / KO, k = i - r*KO;
        int gr = rbase + r;
        int b = gr / NN;
        int node = gr - b*NN;
        sCin[i] = (k < PP) ? x[(b*NN+node)*PP + k]
                           : ebar[(b*NN+node)*DE + (k-PP)];
    }
    __syncthreads();

    {
        const int j = tid & (HID-1);
        const int g = tid >> 7;
        float w[KO];
        #pragma unroll
        for (int k = 0; k < KO; ++k) w[k] = sW[k*HID + j];
        const float bj = sB1[j];
        #pragma unroll
        for (int rr = 0; rr < 8; ++rr) {
            const int r = g*8 + rr;
            const float* e = &sCin[r*KO];
            float a0=0.f,a1=0.f,a2=0.f;
            #pragma unroll
            for (int k = 0; k < KO; k += 3) {
                a0 += w[k+0]*e[k+0];
                a1 += w[k+1]*e[k+1];
                a2 += w[k+2]*e[k+2];
            }
            float v = a0+a1+a2+bj;
            sH1[r*HID + j] = v > 0.f ? v : 0.f;
        }
    }
    __syncthreads();
    for (int i = tid; i < HID*HH2; i += 512) sW[i] = w2[i];
    __syncthreads();

    {
        const int j = tid & (HH2-1);
        const int g = tid >> 6;
        float acc[4];
        #pragma unroll
        for (int rr = 0; rr < 4; ++rr) acc[rr] = sB2[j];
        #pragma unroll
        for (int kc = 0; kc < HID; kc += 32) {
            float w[32];
            #pragma unroll
            for (int kk = 0; kk < 32; ++kk) w[kk] = sW[(kc+kk)*HH2 + j];
            #pragma unroll
            for (int rr = 0; rr < 4; ++rr) {
                const float* h = &sH1[(g*4+rr)*HID + kc];
                float a0=0.f,a1=0.f,a2=0.f,a3=0.f;
                #pragma unroll
                for (int kk = 0; kk < 32; kk += 4) {
                    a0 += w[kk+0]*h[kk+0];
                    a1 += w[kk+1]*h[kk+1];
                    a2 += w[kk+2]*h[kk+2];
                    a3 += w[kk+3]*h[kk+3];
                }
                acc[rr] += (a0+a1)+(a2+a3);
            }
        }
        #pragma unroll
        for (int rr = 0; rr < 4; ++rr) {
            float v = acc[rr];
            sH2t[j*(RT+1) + (g*4+rr)] = v > 0.f ? v : 0.f;
        }
    }
    __syncthreads();

    if (tid < RT*DO) {
        const int r = tid & (RT-1);
        const int c = tid >> 5;
        float a0=0.f,a1=0.f,a2=0.f,a3=0.f;
        #pragma unroll
        for (int k = 0; k < HH2; k += 4) {
            a0 += sH2t[(k+0)*(RT+1)+r]*w3[(k+0)*DO+c];
            a1 += sH2t[(k+1)*(RT+1)+r]*w3[(k+1)*DO+c];
            a2 += sH2t[(k+2)*(RT+1)+r]*w3[(k+2)*DO+c];
            a3 += sH2t[(k+3)*(RT+1)+r]*w3[(k+3)*DO+c];
        }
        float v = (a0+a1)+(a2+a3) + b3[c];
        v = v > 0.f ? v : 0.f;
        int gr = rbase + r;
        int b = gr / NN;
        int node = gr - b*NN;
        o_out[b*(NN*DO) + node*DO + c] = v;
    }
}

// ---------------------------------------------------------------------------
// Classifier (unchanged): 1128 -> 128 relu -> 64 relu -> 5
// ---------------------------------------------------------------------------
__global__ __launch_bounds__(256)
void fc_kernel(const float* __restrict__ o_in,
               const float* __restrict__ w1, const float* __restrict__ b1,
               const float* __restrict__ w2, const float* __restrict__ b2,
               const float* __restrict__ w3, const float* __restrict__ b3,
               float* __restrict__ out)
{
    __shared__ __align__(16) float s_in[NN*DO];
    __shared__ float s_p[256];
    __shared__ float s_h1[HID];
    __shared__ float s_h2[HH2];
    const int b = blockIdx.x, tid = threadIdx.x;

    for (int i = tid; i < NN*DO; i += 256) s_in[i] = o_in[b*(NN*DO) + i];
    __syncthreads();

    {
        const int j = tid & (HID-1);
        const int h = tid >> 7;
        const float4* s4 = (const float4*)&s_in[h*564];
        const float* wbase = w1 + (size_t)(h*564)*HID + j;
        float a0=0.f,a1=0.f,a2=0.f,a3=0.f;
        #pragma unroll 4
        for (int i = 0; i < 141; ++i) {
            float4 v = s4[i];
            const float* wp = wbase + (size_t)i*4*HID;
            a0 += v.x * wp[0];
            a1 += v.y * wp[HID];
            a2 += v.z * wp[2*HID];
            a3 += v.w * wp[3*HID];
        }
        s_p[tid] = (a0+a1)+(a2+a3);
    }
    __syncthreads();
    if (tid < HID) {
        float v = s_p[tid] + s_p[tid+HID] + b1[tid];
        s_h1[tid] = v > 0.f ? v : 0.f;
    }
    __syncthreads();

    {
        const int j = tid & (HH2-1);
        const int q = tid >> 6;
        float acc = 0.f;
        #pragma unroll
        for (int kk = 0; kk < 32; ++kk) {
            int k = q*32 + kk;
            acc += s_h1[k] * w2[k*HH2 + j];
        }
        s_p[tid] = acc;
    }
    __syncthreads();
    if (tid < HH2) {
        float v = s_p[tid] + s_p[tid+64] + s_p[tid+128] + s_p[tid+192] + b2[tid];
        s_h2[tid] = v > 0.f ? v : 0.f;
    }
    __syncthreads();

    if (tid < NT) {
        float acc = b3[tid];
        #pragma unroll
        for (int k = 0; k < HH2; ++k)
            acc += s_h2[k] * w3[k*NT + tid];
        out[b*NT + tid] = acc;
    }
}

extern "C" void kernel_launch(void* const* d_in, const int* in_sizes, int n_in,
                              void* d_out, int out_size, void* d_ws, size_t ws_size,
                              hipStream_t stream) {
    (void)in_sizes; (void)n_in; (void)out_size; (void)ws_size;
    const float* x     = (const float*)d_in[0];
    const float* fr1_w = (const float*)d_in[1];
    const float* fr1_b = (const float*)d_in[2];
    const float* fr2_w = (const float*)d_in[3];
    const float* fr2_b = (const float*)d_in[4];
    const float* fr3_w = (const float*)d_in[5];
    const float* fr3_b = (const float*)d_in[6];
    const float* fo1_w = (const float*)d_in[7];
    const float* fo1_b = (const float*)d_in[8];
    const float* fo2_w = (const float*)d_in[9];
    const float* fo2_b = (const float*)d_in[10];
    const float* fo3_w = (const float*)d_in[11];
    const float* fo3_b = (const float*)d_in[12];
    const float* fc1_w = (const float*)d_in[13];
    const float* fc1_b = (const float*)d_in[14];
    const float* fc2_w = (const float*)d_in[15];
    const float* fc2_b = (const float*)d_in[16];
    const float* fc3_w = (const float*)d_in[17];
    const float* fc3_b = (const float*)d_in[18];

    short* ws_s = (short*)d_ws;
    size_t fbase = ((size_t)SHORT_TOTAL*2 + 15) & ~(size_t)15;
    float* ebar = (float*)((char*)d_ws + fbase);            // [32][188][5]
    float* o_ws = ebar + BB*NN*DE;                          // [32][188][6]

    prep_kernel<<<128, 256, 0, stream>>>(x, fr1_w, fr2_w, fr3_w, ws_s);
    edge_mfma_kernel<<<(BB*NN)/8, 256, 0, stream>>>(ws_s, fr1_b, fr2_b, fr3_b, ebar);
    obj_mlp_kernel<<<ROWS_O/RT, 512, 0, stream>>>(
        x, ebar, fo1_w, fo1_b, fo2_w, fo2_b, fo3_w, fo3_b, o_ws);
    fc_kernel<<<BB, 256, 0, stream>>>(
        o_ws, fc1_w, fc1_b, fc2_w, fc2_b, fc3_w, fc3_b, (float*)d_out);
}